// Round 1
// baseline (367.556 us; speedup 1.0000x reference)
//
#include <hip/hip_runtime.h>

#define B_   32
#define L_   512
#define D_   384
#define M_   (B_*L_)    // 16384 rows
#define KTOT (D_*3)     // 1152 GEMM K

typedef __bf16 bf16x8 __attribute__((ext_vector_type(8)));
typedef float  floatx4 __attribute__((ext_vector_type(4)));

// ---------------- conversion: x fp32 -> bf16 ----------------
__global__ __launch_bounds__(256) void cvt_kernel(const float* __restrict__ x,
                                                  __bf16* __restrict__ xb, int n4)
{
    int i = blockIdx.x * 256 + threadIdx.x;
    if (i >= n4) return;
    const float4 v = ((const float4*)x)[i];
    __bf16* o = xb + (size_t)i * 4;
    o[0] = (__bf16)v.x; o[1] = (__bf16)v.y; o[2] = (__bf16)v.z; o[3] = (__bf16)v.w;
}

// ---------------- weight repack: w[o][i][k] -> Wt[o][k*384+i] bf16 ----------------
__global__ __launch_bounds__(256) void repack_kernel(const float* __restrict__ w,
                                                     __bf16* __restrict__ Wt)
{
    int idx = blockIdx.x * 256 + threadIdx.x;
    if (idx >= D_ * KTOT) return;
    int o  = idx / KTOT;
    int kk = idx - o * KTOT;
    int k  = kk / D_;
    int i  = kk - k * D_;
    Wt[idx] = (__bf16)w[(o * D_ + i) * 3 + k];
}

// ---------------- conv-as-GEMM: C = relu(shiftA @ Wt^T + bias), bf16 in/out ----------------
// A: [M_, 384] bf16 (rows are (b,l)); Wt: [384, 1152] bf16; C: [M_, 384] bf16
#define BM 128
#define BN 128
#define BK 32
#define LDA 40   // padded row stride in bf16 elems (80 B, 16B-aligned, 2-way bank alias only)

__global__ __launch_bounds__(256) void conv_gemm(const __bf16* __restrict__ A,
                                                 const __bf16* __restrict__ W,
                                                 const float* __restrict__ bias,
                                                 __bf16* __restrict__ C)
{
    __shared__ __bf16 As[BM * LDA];
    __shared__ __bf16 Bs[BN * LDA];

    const int n0 = blockIdx.x * BN;        // 0,128,256
    const int m0 = blockIdx.y * BM;        // tile of 128 rows, never crosses batch
    const int b  = m0 >> 9;                // /512
    const int l0 = m0 & 511;

    const int tid  = threadIdx.x;
    const int wave = tid >> 6;
    const int lane = tid & 63;
    const int wm   = (wave >> 1) * 64;
    const int wn   = (wave & 1) * 64;
    const int quad = lane >> 4;
    const int lx   = lane & 15;

    floatx4 acc[4][4];
#pragma unroll
    for (int mi = 0; mi < 4; mi++)
#pragma unroll
        for (int ni = 0; ni < 4; ni++)
#pragma unroll
            for (int r = 0; r < 4; r++) acc[mi][ni][r] = 0.f;

    const int r0 = tid >> 2;          // 0..63
    const int ch = (tid & 3) * 8;     // 0,8,16,24 bf16 offset (16B chunks)

    for (int kt = 0; kt < KTOT / BK; kt++) {
        const int kk0   = kt * BK;
        const int k     = kk0 / D_;       // single shift per K-tile (384 % 32 == 0)
        const int i0    = kk0 - k * D_;
        const int shift = k - 1;
        // stage A (shifted rows, zero outside the sequence)
#pragma unroll
        for (int it = 0; it < 2; it++) {
            int r = r0 + it * 64;
            int l = l0 + r + shift;
            bf16x8 val;
#pragma unroll
            for (int q = 0; q < 8; q++) val[q] = (__bf16)0.f;
            if (l >= 0 && l < L_)
                val = *(const bf16x8*)(A + ((size_t)(b * L_ + l)) * D_ + i0 + ch);
            *(bf16x8*)(&As[r * LDA + ch]) = val;
        }
        // stage B
#pragma unroll
        for (int it = 0; it < 2; it++) {
            int r = r0 + it * 64;
            *(bf16x8*)(&Bs[r * LDA + ch]) =
                *(const bf16x8*)(W + (size_t)(n0 + r) * KTOT + kk0 + ch);
        }
        __syncthreads();

        bf16x8 af[4], bfg[4];
#pragma unroll
        for (int mi = 0; mi < 4; mi++)
            af[mi] = *(const bf16x8*)(&As[(wm + mi * 16 + lx) * LDA + quad * 8]);
#pragma unroll
        for (int ni = 0; ni < 4; ni++)
            bfg[ni] = *(const bf16x8*)(&Bs[(wn + ni * 16 + lx) * LDA + quad * 8]);
#pragma unroll
        for (int mi = 0; mi < 4; mi++)
#pragma unroll
            for (int ni = 0; ni < 4; ni++)
                acc[mi][ni] = __builtin_amdgcn_mfma_f32_16x16x32_bf16(af[mi], bfg[ni], acc[mi][ni], 0, 0, 0);
        __syncthreads();
    }

    // epilogue: bias + relu, C/D layout col=lane&15, row=quad*4+reg
#pragma unroll
    for (int mi = 0; mi < 4; mi++) {
#pragma unroll
        for (int ni = 0; ni < 4; ni++) {
            int col = n0 + wn + ni * 16 + lx;
            float bv = bias[col];
#pragma unroll
            for (int r = 0; r < 4; r++) {
                int row = m0 + wm + mi * 16 + quad * 4 + r;
                float v = acc[mi][ni][r] + bv;
                v = v > 0.f ? v : 0.f;
                C[(size_t)row * D_ + col] = (__bf16)v;
            }
        }
    }
}

// ---------------- LayerNorm over D=384, wave per row ----------------
__global__ __launch_bounds__(256) void ln_kernel(const __bf16* __restrict__ X,
                                                 const float* __restrict__ g,
                                                 const float* __restrict__ bb,
                                                 __bf16* __restrict__ Y)
{
    int row  = blockIdx.x * 4 + (threadIdx.x >> 6);
    int lane = threadIdx.x & 63;
    const __bf16* xr = X + (size_t)row * D_;
    float v[6], s = 0.f, sq = 0.f;
#pragma unroll
    for (int i = 0; i < 6; i++) {
        v[i] = (float)xr[lane + i * 64];
        s += v[i]; sq += v[i] * v[i];
    }
#pragma unroll
    for (int off = 32; off; off >>= 1) { s += __shfl_down(s, off); sq += __shfl_down(sq, off); }
    s = __shfl(s, 0); sq = __shfl(sq, 0);
    float mean = s * (1.f / D_);
    float var  = sq * (1.f / D_) - mean * mean;
    float inv  = rsqrtf(var + 1e-5f);
    __bf16* yr = Y + (size_t)row * D_;
#pragma unroll
    for (int i = 0; i < 6; i++) {
        int c = lane + i * 64;
        yr[c] = (__bf16)((v[i] - mean) * inv * g[c] + bb[c]);
    }
}

// ---------------- linear head D->1, wave per row ----------------
__global__ __launch_bounds__(256) void head_kernel(const __bf16* __restrict__ X,
                                                   const float* __restrict__ w,
                                                   const float* __restrict__ bb,
                                                   float* __restrict__ out)
{
    int row  = blockIdx.x * 4 + (threadIdx.x >> 6);
    int lane = threadIdx.x & 63;
    const __bf16* xr = X + (size_t)row * D_;
    float s = 0.f;
#pragma unroll
    for (int i = 0; i < 6; i++) { int c = lane + i * 64; s += (float)xr[c] * w[c]; }
#pragma unroll
    for (int off = 32; off; off >>= 1) s += __shfl_down(s, off);
    if (lane == 0) out[row] = s + bb[0];
}

// ---------------- cumsum of durations, wave per batch ----------------
__global__ __launch_bounds__(64) void cum_kernel(const int* __restrict__ dur,
                                                 int* __restrict__ cum)
{
    int b = blockIdx.x, lane = threadIdx.x;
    const int* db = dur + b * L_;
    int v[8], s = 0;
#pragma unroll
    for (int i = 0; i < 8; i++) { v[i] = db[lane * 8 + i]; s += v[i]; }
    int ex = s;
#pragma unroll
    for (int off = 1; off < 64; off <<= 1) {
        int n = __shfl_up(ex, off);
        if (lane >= off) ex += n;
    }
    ex -= s;
    int c = ex;
    int* cb = cum + b * L_;
#pragma unroll
    for (int i = 0; i < 8; i++) { c += v[i]; cb[lane * 8 + i] = c; }
}

// ---------------- gather / length-regulate, block per frame ----------------
__global__ __launch_bounds__(128) void gather_kernel(const float* __restrict__ x,
                                                     const int* __restrict__ cum,
                                                     float* __restrict__ out, int T)
{
    int fr = blockIdx.x;
    int b  = fr / T;
    int t  = fr - b * T;
    int tid = threadIdx.x;
    const int* cb = cum + b * L_;
    int total = cb[L_ - 1];
    float4 val = make_float4(0.f, 0.f, 0.f, 0.f);
    if (t < total) {
        int lo = 0, hi = L_;
        while (lo < hi) { int mid = (lo + hi) >> 1; if (cb[mid] > t) hi = mid; else lo = mid + 1; }
        if (tid < 96) val = *(const float4*)(x + ((size_t)(b * L_ + lo)) * D_ + tid * 4);
    }
    if (tid < 96) *(float4*)(out + (size_t)fr * D_ + tid * 4) = val;
}

extern "C" void kernel_launch(void* const* d_in, const int* in_sizes, int n_in,
                              void* d_out, int out_size, void* d_ws, size_t ws_size,
                              hipStream_t stream) {
    const float* x       = (const float*)d_in[0];
    const int*   dur     = (const int*)d_in[1];
    const float* c1a_w   = (const float*)d_in[2];
    const float* c1a_b   = (const float*)d_in[3];
    const float* c1b_w   = (const float*)d_in[4];
    const float* c1b_b   = (const float*)d_in[5];
    const float* ln1_g   = (const float*)d_in[6];
    const float* ln1_b   = (const float*)d_in[7];
    const float* c2a_w   = (const float*)d_in[8];
    const float* c2a_b   = (const float*)d_in[9];
    const float* c2b_w   = (const float*)d_in[10];
    const float* c2b_b   = (const float*)d_in[11];
    const float* ln2_g   = (const float*)d_in[12];
    const float* ln2_b   = (const float*)d_in[13];
    const float* lin_w   = (const float*)d_in[14];
    const float* lin_b   = (const float*)d_in[15];

    const int T = (out_size - B_ * L_) / (B_ * D_);
    float* out_gather = (float*)d_out;
    float* out_dur    = (float*)d_out + (size_t)B_ * T * D_;

    // workspace layout
    char* p = (char*)d_ws;
    __bf16* xb  = (__bf16*)p; p += (size_t)M_ * D_ * 2;
    __bf16* h1  = (__bf16*)p; p += (size_t)M_ * D_ * 2;
    __bf16* h2  = (__bf16*)p; p += (size_t)M_ * D_ * 2;
    __bf16* w1a = (__bf16*)p; p += (size_t)D_ * KTOT * 2;
    __bf16* w1b = (__bf16*)p; p += (size_t)D_ * KTOT * 2;
    __bf16* w2a = (__bf16*)p; p += (size_t)D_ * KTOT * 2;
    __bf16* w2b = (__bf16*)p; p += (size_t)D_ * KTOT * 2;
    int* cum = (int*)p; p += (size_t)B_ * L_ * 4;

    // LR path (independent of predictor chain)
    cum_kernel<<<B_, 64, 0, stream>>>(dur, cum);
    gather_kernel<<<B_ * T, 128, 0, stream>>>(x, cum, out_gather, T);

    // predictor chain
    cvt_kernel<<<(M_ * D_ / 4 + 255) / 256, 256, 0, stream>>>(x, xb, M_ * D_ / 4);
    int rp_blocks = (D_ * KTOT + 255) / 256;
    repack_kernel<<<rp_blocks, 256, 0, stream>>>(c1a_w, w1a);
    repack_kernel<<<rp_blocks, 256, 0, stream>>>(c1b_w, w1b);
    repack_kernel<<<rp_blocks, 256, 0, stream>>>(c2a_w, w2a);
    repack_kernel<<<rp_blocks, 256, 0, stream>>>(c2b_w, w2b);

    dim3 ggrid(D_ / BN, M_ / BM);  // 3 x 128
    conv_gemm<<<ggrid, 256, 0, stream>>>(xb, w1a, c1a_b, h1);
    conv_gemm<<<ggrid, 256, 0, stream>>>(h1, w1b, c1b_b, h2);
    ln_kernel<<<M_ / 4, 256, 0, stream>>>(h2, ln1_g, ln1_b, xb);
    conv_gemm<<<ggrid, 256, 0, stream>>>(xb, w2a, c2a_b, h1);
    conv_gemm<<<ggrid, 256, 0, stream>>>(h1, w2b, c2b_b, h2);
    ln_kernel<<<M_ / 4, 256, 0, stream>>>(h2, ln2_g, ln2_b, xb);
    head_kernel<<<M_ / 4, 256, 0, stream>>>(xb, lin_w, lin_b, out_dur);
}

// Round 2
// 311.127 us; speedup vs baseline: 1.1814x; 1.1814x over previous
//
#include <hip/hip_runtime.h>

#define B_   32
#define L_   512
#define D_   384
#define M_   (B_*L_)    // 16384 rows
#define KTOT (D_*3)     // 1152 GEMM K

typedef __bf16 bf16x8 __attribute__((ext_vector_type(8)));
typedef float  floatx4 __attribute__((ext_vector_type(4)));

// async 16B global -> LDS (direct-to-shared DMA; LDS dest must be wave-uniform base,
// HW scatters lane i to base + i*16)
__device__ static inline void load_lds16(void* lds, const void* g) {
    __builtin_amdgcn_global_load_lds(
        (const __attribute__((address_space(1))) unsigned int*)g,
        (__attribute__((address_space(3))) unsigned int*)lds, 16, 0, 0);
}

// ---------------- conversion: x fp32 -> bf16 ----------------
__global__ __launch_bounds__(256) void cvt_kernel(const float* __restrict__ x,
                                                  __bf16* __restrict__ xb, int n4)
{
    int i = blockIdx.x * 256 + threadIdx.x;
    if (i >= n4) return;
    const float4 v = ((const float4*)x)[i];
    __bf16* o = xb + (size_t)i * 4;
    o[0] = (__bf16)v.x; o[1] = (__bf16)v.y; o[2] = (__bf16)v.z; o[3] = (__bf16)v.w;
}

// ---------------- weight repack (all 4 convs in one launch) ----------------
// w[o][i][k] fp32 -> Wt[o][k*384+i] bf16
__global__ __launch_bounds__(256) void repack4_kernel(const float* __restrict__ wa,
                                                      const float* __restrict__ wb,
                                                      const float* __restrict__ wc,
                                                      const float* __restrict__ wd,
                                                      __bf16* __restrict__ oa,
                                                      __bf16* __restrict__ ob,
                                                      __bf16* __restrict__ oc,
                                                      __bf16* __restrict__ od)
{
    int idx = blockIdx.x * 256 + threadIdx.x;
    if (idx >= D_ * KTOT) return;
    const float* w; __bf16* o_;
    switch (blockIdx.y) {
        case 0:  w = wa; o_ = oa; break;
        case 1:  w = wb; o_ = ob; break;
        case 2:  w = wc; o_ = oc; break;
        default: w = wd; o_ = od; break;
    }
    int o  = idx / KTOT;
    int kk = idx - o * KTOT;
    int k  = kk / D_;
    int i  = kk - k * D_;
    o_[idx] = (__bf16)w[(o * D_ + i) * 3 + k];
}

// ---------------- conv-as-GEMM: C = relu(shiftA @ Wt^T + bias) ----------------
// A: [M_,384] bf16; W: [384,1152] bf16 (o-major, k*384+i); C: [M_,384] bf16
// K-loop: 12 i-tiles of 32; per i-tile stage A once (130-row halo) and the
// 3 shifts' weight columns (128 x 96), then 3 x 16 MFMA accumulating.
#define BM 128
#define BN 128
#define LDA 40   // As row stride in bf16 (80B: ~2-way bank alias only, free)

__global__ __launch_bounds__(256, 2) void conv_gemm(const __bf16* __restrict__ A,
                                                    const __bf16* __restrict__ W,
                                                    const float* __restrict__ bias,
                                                    __bf16* __restrict__ C)
{
    __shared__ __bf16 As[(BM + 2) * LDA];   // 130 halo rows
    __shared__ __bf16 Bs[BN * 96];          // [row][s*32+c], lane-contiguous for load_lds

    const int n0 = blockIdx.x * BN;        // 0,128,256
    const int m0 = blockIdx.y * BM;        // never crosses a sequence (128 | 512)
    const int b  = m0 >> 9;
    const int l0 = m0 & 511;

    const int tid  = threadIdx.x;
    const int wave = tid >> 6;
    const int lane = tid & 63;
    const int wm   = (wave >> 1) * 64;
    const int wn   = (wave & 1) * 64;
    const int quad = lane >> 4;
    const int lx   = lane & 15;

    floatx4 acc[4][4];
#pragma unroll
    for (int mi = 0; mi < 4; mi++)
#pragma unroll
        for (int ni = 0; ni < 4; ni++)
#pragma unroll
            for (int r = 0; r < 4; r++) acc[mi][ni][r] = 0.f;

    // --- B chunk mapping: flat chunk f = (wave*6+j)*64 + lane, f in [0,1536)
    // row = f/12, sub-chunk sc = f%12 -> shift s = sc/4, col c = sc%4
    // global elem offset: (n0+row)*1152 + s*384 + c*8  (+ i0 per iter)
    // LDS dest: wave-uniform base (wave*6+j)*512 elems; lane lands at +lane*8.
    int goff[6];
#pragma unroll
    for (int j = 0; j < 6; j++) {
        int f   = (wave * 6 + j) * 64 + lane;
        int row = f / 12;
        int sc  = f - row * 12;
        int s   = sc >> 2;
        int c   = sc & 3;
        goff[j] = (n0 + row) * KTOT + s * D_ + c * 8;
    }

    // --- A chunk mapping: 130 rows x 4 chunks = 520 chunks of 16B
    const int ca0 = tid;          // 0..255
    const int ca1 = tid + 256;    // 256..511
    const int ca2 = tid + 512;    // 512..519 (tid < 8)

    for (int it = 0; it < 12; it++) {
        const int i0 = it * 32;

        // stage B via direct-to-LDS DMA
#pragma unroll
        for (int j = 0; j < 6; j++)
            load_lds16(&Bs[(wave * 6 + j) * 512], W + goff[j] + i0);

        // stage A halo tile (rows l0-1 .. l0+128), zero outside sequence
        {
#pragma unroll
            for (int cc = 0; cc < 3; cc++) {
                int c = (cc == 0) ? ca0 : (cc == 1) ? ca1 : ca2;
                if (cc == 2 && tid >= 8) break;
                int r = c >> 2, q = c & 3;
                int l = l0 + r - 1;
                bf16x8 val;
#pragma unroll
                for (int z = 0; z < 8; z++) val[z] = (__bf16)0.f;
                if (l >= 0 && l < L_)
                    val = *(const bf16x8*)(A + ((size_t)((b << 9) + l)) * D_ + i0 + q * 8);
                *(bf16x8*)(&As[r * LDA + q * 8]) = val;
            }
        }
        __syncthreads();   // drains vmcnt (load_lds) + lgkmcnt (ds_write)

#pragma unroll
        for (int s = 0; s < 3; s++) {
            bf16x8 af[4], bfg[4];
#pragma unroll
            for (int mi = 0; mi < 4; mi++)
                af[mi] = *(const bf16x8*)(&As[(wm + mi * 16 + lx + s) * LDA + quad * 8]);
#pragma unroll
            for (int ni = 0; ni < 4; ni++)
                bfg[ni] = *(const bf16x8*)(&Bs[(wn + ni * 16 + lx) * 96 + s * 32 + quad * 8]);
#pragma unroll
            for (int mi = 0; mi < 4; mi++)
#pragma unroll
                for (int ni = 0; ni < 4; ni++)
                    acc[mi][ni] = __builtin_amdgcn_mfma_f32_16x16x32_bf16(af[mi], bfg[ni], acc[mi][ni], 0, 0, 0);
        }
        __syncthreads();
    }

    // epilogue: bias + relu; C/D layout col=lane&15, row=quad*4+reg
#pragma unroll
    for (int mi = 0; mi < 4; mi++) {
#pragma unroll
        for (int ni = 0; ni < 4; ni++) {
            int col = n0 + wn + ni * 16 + lx;
            float bv = bias[col];
#pragma unroll
            for (int r = 0; r < 4; r++) {
                int row = m0 + wm + mi * 16 + quad * 4 + r;
                float v = acc[mi][ni][r] + bv;
                v = v > 0.f ? v : 0.f;
                C[(size_t)row * D_ + col] = (__bf16)v;
            }
        }
    }
}

// ---------------- LayerNorm over D=384, wave per row ----------------
__global__ __launch_bounds__(256) void ln_kernel(const __bf16* __restrict__ X,
                                                 const float* __restrict__ g,
                                                 const float* __restrict__ bb,
                                                 __bf16* __restrict__ Y)
{
    int row  = blockIdx.x * 4 + (threadIdx.x >> 6);
    int lane = threadIdx.x & 63;
    const __bf16* xr = X + (size_t)row * D_;
    float v[6], s = 0.f, sq = 0.f;
#pragma unroll
    for (int i = 0; i < 6; i++) {
        v[i] = (float)xr[lane + i * 64];
        s += v[i]; sq += v[i] * v[i];
    }
#pragma unroll
    for (int off = 32; off; off >>= 1) { s += __shfl_down(s, off); sq += __shfl_down(sq, off); }
    s = __shfl(s, 0); sq = __shfl(sq, 0);
    float mean = s * (1.f / D_);
    float var  = sq * (1.f / D_) - mean * mean;
    float inv  = rsqrtf(var + 1e-5f);
    __bf16* yr = Y + (size_t)row * D_;
#pragma unroll
    for (int i = 0; i < 6; i++) {
        int c = lane + i * 64;
        yr[c] = (__bf16)((v[i] - mean) * inv * g[c] + bb[c]);
    }
}

// ---------------- linear head D->1, wave per row ----------------
__global__ __launch_bounds__(256) void head_kernel(const __bf16* __restrict__ X,
                                                   const float* __restrict__ w,
                                                   const float* __restrict__ bb,
                                                   float* __restrict__ out)
{
    int row  = blockIdx.x * 4 + (threadIdx.x >> 6);
    int lane = threadIdx.x & 63;
    const __bf16* xr = X + (size_t)row * D_;
    float s = 0.f;
#pragma unroll
    for (int i = 0; i < 6; i++) { int c = lane + i * 64; s += (float)xr[c] * w[c]; }
#pragma unroll
    for (int off = 32; off; off >>= 1) s += __shfl_down(s, off);
    if (lane == 0) out[row] = s + bb[0];
}

// ---------------- cumsum of durations, wave per batch ----------------
__global__ __launch_bounds__(64) void cum_kernel(const int* __restrict__ dur,
                                                 int* __restrict__ cum)
{
    int b = blockIdx.x, lane = threadIdx.x;
    const int* db = dur + b * L_;
    int v[8], s = 0;
#pragma unroll
    for (int i = 0; i < 8; i++) { v[i] = db[lane * 8 + i]; s += v[i]; }
    int ex = s;
#pragma unroll
    for (int off = 1; off < 64; off <<= 1) {
        int n = __shfl_up(ex, off);
        if (lane >= off) ex += n;
    }
    ex -= s;
    int c = ex;
    int* cb = cum + b * L_;
#pragma unroll
    for (int i = 0; i < 8; i++) { c += v[i]; cb[lane * 8 + i] = c; }
}

// ---------------- gather / length-regulate, block per frame (HBM-write-bound) ----------------
__global__ __launch_bounds__(128) void gather_kernel(const float* __restrict__ x,
                                                     const int* __restrict__ cum,
                                                     float* __restrict__ out, int T)
{
    int fr = blockIdx.x;
    int b  = fr / T;
    int t  = fr - b * T;
    int tid = threadIdx.x;
    const int* cb = cum + b * L_;
    int total = cb[L_ - 1];
    float4 val = make_float4(0.f, 0.f, 0.f, 0.f);
    if (t < total) {
        int lo = 0, hi = L_;
        while (lo < hi) { int mid = (lo + hi) >> 1; if (cb[mid] > t) hi = mid; else lo = mid + 1; }
        if (tid < 96) val = *(const float4*)(x + ((size_t)(b * L_ + lo)) * D_ + tid * 4);
    }
    if (tid < 96) *(float4*)(out + (size_t)fr * D_ + tid * 4) = val;
}

extern "C" void kernel_launch(void* const* d_in, const int* in_sizes, int n_in,
                              void* d_out, int out_size, void* d_ws, size_t ws_size,
                              hipStream_t stream) {
    const float* x       = (const float*)d_in[0];
    const int*   dur     = (const int*)d_in[1];
    const float* c1a_w   = (const float*)d_in[2];
    const float* c1a_b   = (const float*)d_in[3];
    const float* c1b_w   = (const float*)d_in[4];
    const float* c1b_b   = (const float*)d_in[5];
    const float* ln1_g   = (const float*)d_in[6];
    const float* ln1_b   = (const float*)d_in[7];
    const float* c2a_w   = (const float*)d_in[8];
    const float* c2a_b   = (const float*)d_in[9];
    const float* c2b_w   = (const float*)d_in[10];
    const float* c2b_b   = (const float*)d_in[11];
    const float* ln2_g   = (const float*)d_in[12];
    const float* ln2_b   = (const float*)d_in[13];
    const float* lin_w   = (const float*)d_in[14];
    const float* lin_b   = (const float*)d_in[15];

    const int T = (out_size - B_ * L_) / (B_ * D_);
    float* out_gather = (float*)d_out;
    float* out_dur    = (float*)d_out + (size_t)B_ * T * D_;

    // workspace layout
    char* p = (char*)d_ws;
    __bf16* xb  = (__bf16*)p; p += (size_t)M_ * D_ * 2;
    __bf16* h1  = (__bf16*)p; p += (size_t)M_ * D_ * 2;
    __bf16* h2  = (__bf16*)p; p += (size_t)M_ * D_ * 2;
    __bf16* w1a = (__bf16*)p; p += (size_t)D_ * KTOT * 2;
    __bf16* w1b = (__bf16*)p; p += (size_t)D_ * KTOT * 2;
    __bf16* w2a = (__bf16*)p; p += (size_t)D_ * KTOT * 2;
    __bf16* w2b = (__bf16*)p; p += (size_t)D_ * KTOT * 2;
    int* cum = (int*)p; p += (size_t)B_ * L_ * 4;

    // LR path (independent of predictor chain)
    cum_kernel<<<B_, 64, 0, stream>>>(dur, cum);
    gather_kernel<<<B_ * T, 128, 0, stream>>>(x, cum, out_gather, T);

    // predictor chain
    cvt_kernel<<<(M_ * D_ / 4 + 255) / 256, 256, 0, stream>>>(x, xb, M_ * D_ / 4);
    dim3 rpgrid((D_ * KTOT + 255) / 256, 4);
    repack4_kernel<<<rpgrid, 256, 0, stream>>>(c1a_w, c1b_w, c2a_w, c2b_w, w1a, w1b, w2a, w2b);

    dim3 ggrid(D_ / BN, M_ / BM);  // 3 x 128
    conv_gemm<<<ggrid, 256, 0, stream>>>(xb, w1a, c1a_b, h1);
    conv_gemm<<<ggrid, 256, 0, stream>>>(h1, w1b, c1b_b, h2);
    ln_kernel<<<M_ / 4, 256, 0, stream>>>(h2, ln1_g, ln1_b, xb);
    conv_gemm<<<ggrid, 256, 0, stream>>>(xb, w2a, c2a_b, h1);
    conv_gemm<<<ggrid, 256, 0, stream>>>(h1, w2b, c2b_b, h2);
    ln_kernel<<<M_ / 4, 256, 0, stream>>>(h2, ln2_g, ln2_b, xb);
    head_kernel<<<M_ / 4, 256, 0, stream>>>(xb, lin_w, lin_b, out_dur);
}